// Round 5
// baseline (252.232 us; speedup 1.0000x reference)
//
#include <hip/hip_runtime.h>

#define INF_F 3.402823466e+38f

struct Params {
  const float* points;
  const int* idx[4];
  const float* feats[4];
  float2* hdr;      // [N][4][3] (weight, idx-as-float)
  int* counts;      // [cellsTot + histSize]
  int* starts;      // [lenCounts + 1]
  int* fillpos;     // [lenCounts]
  int* cellList;    // [totM] per-scale-local candidate indices
  int* perm;        // [N] Morton order
  float* outp;
  int N, totM, totC;
  int M[4], C[4], Mbase[4], colOff[4], G[4], cellBase[4];
  int cellsTot, histSize, lenCounts;
  float ve[4], hv[4], inv_ve[4];
  float off;
};

// ---------------- Morton bucket (performance-only permutation) --------------
__device__ __forceinline__ int spread3(int v) {
  return (v & 1) | ((v & 2) << 2) | ((v & 4) << 4) | ((v & 8) << 6);
}
__device__ __forceinline__ int point_bucket(const float* pts, int i) {
  float x = pts[i * 3 + 0], y = pts[i * 3 + 1], z = pts[i * 3 + 2];
  float sc = 16.0f / 0.96f;
  int cx = (int)((x + 0.48f) * sc);
  int cy = (int)((y + 0.48f) * sc);
  int cz = (int)((z + 0.48f) * sc);
  cx = cx < 0 ? 0 : (cx > 15 ? 15 : cx);
  cy = cy < 0 ? 0 : (cy > 15 ? 15 : cy);
  cz = cz < 0 ? 0 : (cz > 15 ? 15 : cz);
  return spread3(cx) | (spread3(cy) << 1) | (spread3(cz) << 2);  // 12-bit morton
}

// ---------------- K1: zero counts -------------------------------------------
__global__ __launch_bounds__(256) void zero_kernel(Params pr) {
  int t = blockIdx.x * 256 + threadIdx.x;
  if (t < pr.lenCounts) pr.counts[t] = 0;
}

// ---------------- K2: count candidates per cell + points per Morton bucket --
__global__ __launch_bounds__(256) void count_kernel(Params pr) {
  int t = blockIdx.x * 256 + threadIdx.x;
  if (t < pr.totM) {
    int s = (t >= pr.Mbase[1]) + (t >= pr.Mbase[2]) + (t >= pr.Mbase[3]);
    int m = t - pr.Mbase[s];
    const int* id = pr.idx[s] + (size_t)m * 4;
    int G = pr.G[s];
    int cell = (id[1] * G + id[2]) * G + id[3];
    atomicAdd(&pr.counts[pr.cellBase[s] + cell], 1);
  } else if (t < pr.totM + pr.N) {
    int i = t - pr.totM;
    atomicAdd(&pr.counts[pr.cellsTot + point_bucket(pr.points, i)], 1);
  }
}

// ---------------- K3: exclusive scan of counts (1 block, 1024 threads) ------
__global__ __launch_bounds__(1024) void scan_kernel(Params pr) {
  __shared__ int wtot[16];
  int tid = threadIdx.x;
  int len = pr.lenCounts;
  int chunk = (len + 1023) >> 10;
  int beg = tid * chunk; if (beg > len) beg = len;
  int end = beg + chunk; if (end > len) end = len;
  int sum = 0;
  for (int j = beg; j < end; ++j) sum += pr.counts[j];
  int lane = tid & 63, wv = tid >> 6;
  int inc = sum;
  for (int off = 1; off < 64; off <<= 1) {
    int u = __shfl_up(inc, off);
    if (lane >= off) inc += u;
  }
  if (lane == 63) wtot[wv] = inc;
  __syncthreads();
  int wbase = 0;
  for (int w = 0; w < 16; ++w) wbase += (w < wv) ? wtot[w] : 0;
  int excl = wbase + inc - sum;
  int run = excl;
  for (int j = beg; j < end; ++j) {
    int c = pr.counts[j];
    pr.starts[j] = run;
    pr.fillpos[j] = run;
    run += c;
  }
  if (end == len) pr.starts[len] = run;   // duplicate same-value writes OK
}

// ---------------- K4: fill CSR lists + Morton permutation -------------------
__global__ __launch_bounds__(256) void fill_kernel(Params pr) {
  int t = blockIdx.x * 256 + threadIdx.x;
  if (t < pr.totM) {
    int s = (t >= pr.Mbase[1]) + (t >= pr.Mbase[2]) + (t >= pr.Mbase[3]);
    int m = t - pr.Mbase[s];
    const int* id = pr.idx[s] + (size_t)m * 4;
    int G = pr.G[s];
    int cell = (id[1] * G + id[2]) * G + id[3];
    int pos = atomicAdd(&pr.fillpos[pr.cellBase[s] + cell], 1);
    pr.cellList[pos] = m;
  } else if (t < pr.totM + pr.N) {
    int i = t - pr.totM;
    int pos = atomicAdd(&pr.fillpos[pr.cellsTot + point_bucket(pr.points, i)], 1);
    pr.perm[pos - pr.totM] = i;
  }
}

// ---------------- K5: exact 3-NN via expanding Chebyshev shells -------------
__device__ __forceinline__ bool lexlt(float da, int ia, float db, int ib) {
  return da < db || (da == db && ia < ib);
}

__global__ __launch_bounds__(256) void search_kernel(Params pr) {
#pragma clang fp contract(off)
  int t = blockIdx.x * 256 + threadIdx.x;
  if (t >= 4 * pr.N) return;
  int s = t / pr.N;            // wave-uniform when N % 64 == 0
  int slot = t - s * pr.N;
  int pid = pr.perm[slot];
  float px = pr.points[pid * 3 + 0];
  float py = pr.points[pid * 3 + 1];
  float pz = pr.points[pid * 3 + 2];
  int G = pr.G[s];
  float ve = pr.ve[s], hv = pr.hv[s], off = pr.off, inv = pr.inv_ve[s];
  int cx = (int)((px - off) * inv); cx = cx < 0 ? 0 : (cx > G - 1 ? G - 1 : cx);
  int cy = (int)((py - off) * inv); cy = cy < 0 ? 0 : (cy > G - 1 ? G - 1 : cy);
  int cz = (int)((pz - off) * inv); cz = cz < 0 ? 0 : (cz > G - 1 ? G - 1 : cz);
  const int* starts = pr.starts + pr.cellBase[s];
  const int* clist = pr.cellList;

  float bd0 = INF_F, bd1 = INF_F, bd2 = INF_F;
  int bi0 = 0, bi1 = 0, bi2 = 0;

  for (int r = 0; r <= 2 * G; ++r) {
    int x0 = cx - r; if (x0 < 0) x0 = 0;
    int x1 = cx + r; if (x1 > G - 1) x1 = G - 1;
    int y0 = cy - r; if (y0 < 0) y0 = 0;
    int y1 = cy + r; if (y1 > G - 1) y1 = G - 1;
    int z0 = cz - r; if (z0 < 0) z0 = 0;
    int z1 = cz + r; if (z1 > G - 1) z1 = G - 1;
    for (int ix = x0; ix <= x1; ++ix) {
      int adx = ix - cx; adx = adx < 0 ? -adx : adx;
      float qx = ((float)ix * ve + off) + hv;   // exact reference op order
      float dxv = px - qx;
      float dx2 = dxv * dxv;
      for (int iy = y0; iy <= y1; ++iy) {
        int ady = iy - cy; ady = ady < 0 ? -ady : ady;
        int ad = adx > ady ? adx : ady;
        float qy = ((float)iy * ve + off) + hv;
        float dyv = py - qy;
        float dxy2 = fmaf(dyv, dyv, dx2);
        int rowBase = (ix * G + iy) * G;

        auto visit = [&](int iz) {
          float qz = ((float)iz * ve + off) + hv;
          float dzv = pz - qz;
          float d = fmaf(dzv, dzv, dxy2);       // matches round-4 passing formula
          int c = rowBase + iz;
          int a = starts[c], b = starts[c + 1];
          for (int e = a; e < b; ++e) {
            int m = clist[e];
            if (lexlt(d, m, bd2, bi2)) {        // (d, idx) lex = top_k stability
              bool l1 = lexlt(d, m, bd1, bi1), l0 = lexlt(d, m, bd0, bi0);
              bd2 = l1 ? bd1 : d;  bi2 = l1 ? bi1 : m;
              bd1 = l0 ? bd0 : (l1 ? d : bd1);
              bi1 = l0 ? bi0 : (l1 ? m : bi1);
              bd0 = l0 ? d : bd0;  bi0 = l0 ? m : bi0;
            }
          }
        };

        if (ad == r) {                           // new column: full z-range
          for (int iz = z0; iz <= z1; ++iz) visit(iz);
        } else {                                 // interior column: only z = cz±r
          int iz = cz - r;
          if (iz >= 0) visit(iz);
          iz = cz + r;
          if (iz <= G - 1) visit(iz);
        }
      }
    }
    bool covered = (x0 == 0 && y0 == 0 && z0 == 0 &&
                    x1 == G - 1 && y1 == G - 1 && z1 == G - 1);
    if (covered) break;
    if (bd2 < INF_F) {
      // unscanned cells have Chebyshev >= r+1 -> true dist >= (r+0.5)*ve;
      // 0.499 leaves 0.2% conservative margin >> fp rounding
      float bound = ((float)r + 0.499f) * ve;
      if (bd2 < bound * bound) break;
    }
  }

  float r0 = 1.0f / (bd0 + 1e-8f);
  float r1 = 1.0f / (bd1 + 1e-8f);
  float r2 = 1.0f / (bd2 + 1e-8f);
  float sum = (r0 + r1) + r2;
  float2* h = pr.hdr + ((size_t)slot * 4 + s) * 3;
  h[0] = make_float2(r0 / sum, __int_as_float(bi0));
  h[1] = make_float2(r1 / sum, __int_as_float(bi1));
  h[2] = make_float2(r2 / sum, __int_as_float(bi2));
}

// ---------------- K6: weighted feature gather (block per point) -------------
__global__ __launch_bounds__(128) void gather_kernel(Params pr) {
#pragma clang fp contract(off)
  int slot = blockIdx.x;
  int pid = pr.perm[slot];
  const float2* h = pr.hdr + (size_t)slot * 12;
  int nC4 = pr.totC >> 2;
  for (int c4 = threadIdx.x; c4 < nC4; c4 += 128) {
    int c = c4 << 2;
    int gs = (c >= pr.colOff[1]) + (c >= pr.colOff[2]) + (c >= pr.colOff[3]);
    int cc = c - pr.colOff[gs];
    float2 h0 = h[gs * 3 + 0], h1 = h[gs * 3 + 1], h2 = h[gs * 3 + 2];
    const float* F = pr.feats[gs];
    int C = pr.C[gs];
    const float4 a  = *(const float4*)(F + (size_t)__float_as_int(h0.y) * C + cc);
    const float4 bq = *(const float4*)(F + (size_t)__float_as_int(h1.y) * C + cc);
    const float4 cq = *(const float4*)(F + (size_t)__float_as_int(h2.y) * C + cc);
    float4 v;
    v.x = (h0.x * a.x + h1.x * bq.x) + h2.x * cq.x;
    v.y = (h0.x * a.y + h1.x * bq.y) + h2.x * cq.y;
    v.z = (h0.x * a.z + h1.x * bq.z) + h2.x * cq.z;
    v.w = (h0.x * a.w + h1.x * bq.w) + h2.x * cq.w;
    *(float4*)(pr.outp + (size_t)pid * pr.totC + c) = v;
  }
}

extern "C" void kernel_launch(void* const* d_in, const int* in_sizes, int n_in,
                              void* d_out, int out_size, void* d_ws, size_t ws_size,
                              hipStream_t stream) {
  (void)n_in; (void)out_size; (void)ws_size;
  Params pr;
  pr.points = (const float*)d_in[0];
  pr.N = in_sizes[0] / 3;
  static const int SC[4] = {2, 4, 8, 16};
  int totM = 0, totC = 0, cellsTot = 0;
  for (int s = 0; s < 4; ++s) {
    pr.idx[s] = (const int*)d_in[2 + 2 * s];
    pr.feats[s] = (const float*)d_in[3 + 2 * s];
    pr.M[s] = in_sizes[2 + 2 * s] / 4;
    pr.C[s] = in_sizes[3 + 2 * s] / pr.M[s];
    pr.Mbase[s] = totM;
    pr.colOff[s] = totC;
    totM += pr.M[s];
    totC += pr.C[s];
    int G = 64 / SC[s];
    pr.G[s] = G;
    pr.cellBase[s] = cellsTot;
    cellsTot += G * G * G;
    float ve = 0.015f * (float)SC[s];
    pr.ve[s] = ve;
    pr.hv[s] = 0.5f * ve;
    pr.inv_ve[s] = 1.0f / ve;
  }
  pr.off = (-0.5f * 0.015f) * 64.0f;   // exact f32 replication of OFFSET
  pr.totM = totM;
  pr.totC = totC;
  pr.cellsTot = cellsTot;
  pr.histSize = 4096;
  pr.lenCounts = cellsTot + 4096;

  char* ws = (char*)d_ws;
  size_t o = 0;
  pr.hdr = (float2*)(ws + o);     o += (size_t)pr.N * 12 * 8;        // 8B-aligned first
  pr.counts = (int*)(ws + o);     o += (size_t)pr.lenCounts * 4;
  pr.starts = (int*)(ws + o);     o += (size_t)(pr.lenCounts + 1) * 4;
  pr.fillpos = (int*)(ws + o);    o += (size_t)pr.lenCounts * 4;
  pr.cellList = (int*)(ws + o);   o += (size_t)totM * 4;
  pr.perm = (int*)(ws + o);       o += (size_t)pr.N * 4;
  pr.outp = (float*)d_out;

  int cntThreads = totM + pr.N;
  hipLaunchKernelGGL(zero_kernel, dim3((pr.lenCounts + 255) / 256), dim3(256), 0, stream, pr);
  hipLaunchKernelGGL(count_kernel, dim3((cntThreads + 255) / 256), dim3(256), 0, stream, pr);
  hipLaunchKernelGGL(scan_kernel, dim3(1), dim3(1024), 0, stream, pr);
  hipLaunchKernelGGL(fill_kernel, dim3((cntThreads + 255) / 256), dim3(256), 0, stream, pr);
  hipLaunchKernelGGL(search_kernel, dim3((4 * pr.N + 255) / 256), dim3(256), 0, stream, pr);
  hipLaunchKernelGGL(gather_kernel, dim3(pr.N), dim3(128), 0, stream, pr);
}